// Round 19
// baseline (121.599 us; speedup 1.0000x reference)
//
#include <hip/hip_runtime.h>

#define NN    4096
#define MM    8191   // 2*NN - 1 (valid rows 0..8190)
#define BB    256
#define NBLK  256    // gemm blocks; 32 rows each

typedef short bf16x8 __attribute__((ext_vector_type(8)));
typedef float f32x4  __attribute__((ext_vector_type(4)));

// round-to-nearest-even pack of two f32 -> 2x bf16 in one uint
__device__ __forceinline__ unsigned pack2bf(float lo, float hi) {
    unsigned a = __float_as_uint(lo);
    unsigned b = __float_as_uint(hi);
    a += 0x7fffu + ((a >> 16) & 1u);
    b += 0x7fffu + ((b >> 16) & 1u);
    return (a >> 16) | (b & 0xffff0000u);
}

// 8 f32 (0/1-valued subtree entries) -> 8 bf16 by truncation (exact for 0/1)
__device__ __forceinline__ bf16x8 cvt8(float4 a, float4 b) {
    bf16x8 r;
    r[0] = (short)(__float_as_uint(a.x) >> 16);
    r[1] = (short)(__float_as_uint(a.y) >> 16);
    r[2] = (short)(__float_as_uint(a.z) >> 16);
    r[3] = (short)(__float_as_uint(a.w) >> 16);
    r[4] = (short)(__float_as_uint(b.x) >> 16);
    r[5] = (short)(__float_as_uint(b.y) >> 16);
    r[6] = (short)(__float_as_uint(b.z) >> 16);
    r[7] = (short)(__float_as_uint(b.w) >> 16);
    return r;
}

// ---------------------------------------------------------------------------
// k_prep: zero part2[256*256]; ddt[b][n] = bf16(d1[n][b]-d2[n][b]) (2 MB,
// TRANSPOSED so the gemm B-operand is k-contiguous per column).
// 256 blocks x 256 thr; block bn handles n = bn*16..+15; thread = col b.
// Reads coalesced (row-major d1/d2); writes 32 B/thread.
// ---------------------------------------------------------------------------
__global__ __launch_bounds__(256) void k_prep(const float* __restrict__ d1,
                                              const float* __restrict__ d2,
                                              float* __restrict__ part2,
                                              char* __restrict__ ddt) {
    const int bn = blockIdx.x;
    const int b  = threadIdx.x;
    const int n0 = bn * 16;
    part2[bn * 256 + b] = 0.0f;

    float df[16];
    #pragma unroll
    for (int j = 0; j < 16; ++j) {
        int idx = (n0 + j) * BB + b;
        df[j] = d1[idx] - d2[idx];
    }
    uint4 w0, w1;
    w0.x = pack2bf(df[0], df[1]);  w0.y = pack2bf(df[2], df[3]);
    w0.z = pack2bf(df[4], df[5]);  w0.w = pack2bf(df[6], df[7]);
    w1.x = pack2bf(df[8], df[9]);  w1.y = pack2bf(df[10], df[11]);
    w1.z = pack2bf(df[12], df[13]); w1.w = pack2bf(df[14], df[15]);
    uint4* dst = (uint4*)(ddt + (size_t)b * (NN * 2) + n0 * 2);
    dst[0] = w0;
    dst[1] = w1;
}

// ---------------------------------------------------------------------------
// k_gemm: md = subtree @ dd as dense bf16 MFMA GEMM (R18 post-mortem: kill
// the gather entirely — 17.2 GFLOP is ~2 us of MFMA pipe, free under the
// mandatory 21 us subtree stream).
// 256 blocks x 512 thr (8 waves, 2x4 wave grid; wave = 16 rows x 64 cols).
// K-loop BK=64, B-chunk (64k x 256col bf16 = 32 KB) double-buffered in LDS,
// XOR-swizzled (slot^=(col&7)) for conflict-free ds_read_b128 (G4/T2,
// staged linear-dest + swizzled-src per rule #21). A-frags load straight
// from the HBM stream (0/1 -> bf16 exact). Epilogue: w_v[m]*|md| with the
// verified C/D layout (col=lane&15, row=(lane>>4)*4+reg; m89), shfl_xor
// reduce, per-block part2 row (no global atomics).
// ---------------------------------------------------------------------------
__global__ __launch_bounds__(512) void k_gemm(
        const float* __restrict__ subtree,
        const char* __restrict__ ddt,
        const float* __restrict__ param,
        const int*   __restrict__ parents,
        float* __restrict__ part2) {
    __shared__ uint4 lds_b[2][2048];     // 2 x 32 KB B-chunks
    __shared__ float s_part[BB];
    __shared__ float wv_s[32];
    const int tid = threadIdx.x;
    const int w   = tid >> 6;
    const int l   = tid & 63;
    const int rb  = w & 1;               // row band (16 rows)
    const int cb  = w >> 1;              // col band (64 cols)
    const int m0  = blockIdx.x * 32;

    if (tid < BB) s_part[tid] = 0.0f;
    if (tid < 32) {
        int m = m0 + tid;
        wv_s[tid] = (m < MM) ? (param[parents[m]] - param[m]) : 0.0f;
    }

    // stage(bufsel, k0): LDS slot j16 of col holds global k-slot j16^(col&7)
    #define STAGE(bufsel, k0)                                                \
    {                                                                        \
        _Pragma("unroll")                                                    \
        for (int i = 0; i < 4; ++i) {                                        \
            int S   = tid + i * 512;                                         \
            int col = S >> 3, j16 = S & 7;                                   \
            const uint4* src = (const uint4*)(ddt + (size_t)col * (NN * 2)   \
                               + (k0) * 2 + ((j16 ^ (col & 7)) << 4));       \
            lds_b[bufsel][col * 8 + j16] = *src;                             \
        }                                                                    \
    }

    int rowg = m0 + rb * 16 + (l & 15);
    if (rowg >= MM) rowg = MM - 1;
    const float4* Arow = (const float4*)(subtree + (size_t)rowg * NN) + (l >> 4) * 2;

    f32x4 acc[4] = {{0,0,0,0},{0,0,0,0},{0,0,0,0},{0,0,0,0}};

    STAGE(0, 0);
    __syncthreads();

    int buf = 0;
    #pragma unroll 1
    for (int t = 0; t < 64; ++t) {
        const int k0 = t * 64;
        if (t < 63) STAGE(buf ^ 1, k0 + 64);

        // A-frags: all 4 float4 issued up front (kk=0 and kk=32)
        const float4* Ap = Arow + (k0 >> 2);
        float4 u00 = Ap[0], u01 = Ap[1];
        float4 u10 = Ap[8], u11 = Ap[9];
        bf16x8 a0 = cvt8(u00, u01);
        bf16x8 a1 = cvt8(u10, u11);

        const char* B = (const char*)lds_b[buf];
        #pragma unroll
        for (int f = 0; f < 4; ++f) {
            int col = cb * 64 + f * 16 + (l & 15);
            int c7  = col & 7;
            bf16x8 b0 = *(const bf16x8*)(B + col * 128 + ((((l >> 4))     ^ c7) << 4));
            bf16x8 b1 = *(const bf16x8*)(B + col * 128 + (((4 + (l >> 4)) ^ c7) << 4));
            acc[f] = __builtin_amdgcn_mfma_f32_16x16x32_bf16(a0, b0, acc[f], 0, 0, 0);
            acc[f] = __builtin_amdgcn_mfma_f32_16x16x32_bf16(a1, b1, acc[f], 0, 0, 0);
        }
        __syncthreads();
        buf ^= 1;
    }
    #undef STAGE

    // epilogue: p[col] += sum_r wv[row_r] * |acc|
    #pragma unroll
    for (int f = 0; f < 4; ++f) {
        int col = cb * 64 + f * 16 + (l & 15);
        float sf = 0.0f;
        #pragma unroll
        for (int r = 0; r < 4; ++r) {
            int rl = rb * 16 + (l >> 4) * 4 + r;
            sf += wv_s[rl] * fabsf(acc[f][r]);
        }
        sf += __shfl_xor(sf, 16, 64);
        sf += __shfl_xor(sf, 32, 64);
        if ((l >> 4) == 0) atomicAdd(&s_part[col], sf);
    }
    __syncthreads();
    if (tid < BB) part2[(size_t)blockIdx.x * BB + tid] = s_part[tid];
}

// ---------------------------------------------------------------------------
// k_finalize: 1024 thr; (sl,b): sl sums 64 of the 256 part2 rows 8-deep;
// LDS-reduce; out = sum_b (ot[b] - 0.5*w1[b])^2.
// ---------------------------------------------------------------------------
__global__ __launch_bounds__(1024) void k_finalize(const float* __restrict__ part2,
                                                   const float* __restrict__ ot,
                                                   float* __restrict__ out) {
    __shared__ float s_red[4][BB];
    __shared__ float s_sq[16];
    const int tid = threadIdx.x;
    const int sl = tid >> 8, b = tid & 255;

    float a0 = 0.f, a1 = 0.f, a2 = 0.f, a3 = 0.f;
    float a4 = 0.f, a5 = 0.f, a6 = 0.f, a7 = 0.f;
    #pragma unroll
    for (int jj = 0; jj < 64; jj += 8) {
        int row = sl * 64 + jj;
        a0 += part2[(row    ) * BB + b];
        a1 += part2[(row + 1) * BB + b];
        a2 += part2[(row + 2) * BB + b];
        a3 += part2[(row + 3) * BB + b];
        a4 += part2[(row + 4) * BB + b];
        a5 += part2[(row + 5) * BB + b];
        a6 += part2[(row + 6) * BB + b];
        a7 += part2[(row + 7) * BB + b];
    }
    s_red[sl][b] = ((a0 + a1) + (a2 + a3)) + ((a4 + a5) + (a6 + a7));
    __syncthreads();

    float v = 0.0f;
    if (sl == 0) {
        float w1 = (s_red[0][b] + s_red[1][b]) + (s_red[2][b] + s_red[3][b]);
        float e = ot[b] - 0.5f * w1;
        v = e * e;
    }
    #pragma unroll
    for (int off = 32; off > 0; off >>= 1) v += __shfl_down(v, off, 64);
    if ((tid & 63) == 0) s_sq[tid >> 6] = v;
    __syncthreads();
    if (tid == 0) out[0] = (s_sq[0] + s_sq[1]) + (s_sq[2] + s_sq[3]);
}

// ---------------------------------------------------------------------------
extern "C" void kernel_launch(void* const* d_in, const int* in_sizes, int n_in,
                              void* d_out, int out_size, void* d_ws, size_t ws_size,
                              hipStream_t stream) {
    const float* d1      = (const float*)d_in[0];
    const float* d2      = (const float*)d_in[1];
    const float* ot      = (const float*)d_in[2];
    const float* subtree = (const float*)d_in[3];
    const float* param   = (const float*)d_in[4];
    const int*   parents = (const int*)d_in[5];

    char* wsb = (char*)d_ws;
    float* part2 = (float*)wsb;                      // 256*256 f = 256 KB
    char*  ddt   = wsb + (size_t)NBLK * BB * 4;      // 2 MB bf16 [b][n]

    k_prep<<<256, 256, 0, stream>>>(d1, d2, part2, ddt);
    k_gemm<<<NBLK, 512, 0, stream>>>(subtree, ddt, param, parents, part2);
    k_finalize<<<1, 1024, 0, stream>>>(part2, ot, (float*)d_out);
}